// Round 4
// baseline (73.275 us; speedup 1.0000x reference)
//
#include <hip/hip_runtime.h>
#include <math.h>

#define EPS 1e-6f
#define CAP 1024
#define BB 64
#define LL 1024
#define CC 512
#define LCH 16
#define LPC (LL / LCH) /* 64 rows per chunk */

typedef float f32x4 __attribute__((ext_vector_type(4)));

// ---------- kernel 1: partial sums over l-chunks -----------------------------
// grid = BB*LCH blocks, 128 threads; thread t owns 4 consecutive c (float4)
__global__ __launch_bounds__(128) void k_partial(const float* __restrict__ x,
                          float* __restrict__ psum, float* __restrict__ psq) {
    const int blk = blockIdx.x;            // b*LCH + ch
    const int b = blk / LCH, ch = blk % LCH;
    const int c = threadIdx.x * 4;
    const f32x4* xp = (const f32x4*)(x + ((size_t)b * LL + (size_t)ch * LPC) * CC + c);
    f32x4 s = (f32x4)0.f;
    f32x4 q = (f32x4)0.f;
#pragma unroll 8
    for (int l = 0; l < LPC; ++l) {
        f32x4 v = xp[(size_t)l * (CC / 4)];
        s += v;
        q += v * v;
    }
    *(f32x4*)(psum + (size_t)blk * CC + c) = s;
    *(f32x4*)(psq  + (size_t)blk * CC + c) = q;
}

// ---------- helper: reduce per-sample stats from partials --------------------
__device__ inline void reduce_stats(const float* __restrict__ psum,
                                    const float* __restrict__ psq,
                                    int b, int c4, f32x4& m, f32x4& g) {
    f32x4 s = (f32x4)0.f;
    f32x4 q = (f32x4)0.f;
#pragma unroll
    for (int ch = 0; ch < LCH; ++ch) {
        s += ((const f32x4*)(psum + (size_t)(b * LCH + ch) * CC))[c4];
        q += ((const f32x4*)(psq  + (size_t)(b * LCH + ch) * CC))[c4];
    }
    const float inv_n  = 1.0f / (float)LL;
    const float inv_n1 = 1.0f / (float)(LL - 1);
    m = s * inv_n;
#pragma unroll
    for (int j = 0; j < 4; ++j) {
        float var = (q[j] - (float)LL * m[j] * m[j]) * inv_n1;
        g[j] = sqrtf(fmaxf(var, 0.f) + EPS);
    }
}

// ---------- kernel 2 (fused): index + stats finalize + coeffs + apply --------
// grid = BB*LCH blocks, 128 threads; block (b,ch) applies to rows [ch*64, ch*64+64)
__global__ __launch_bounds__(128) void k_apply(const float* __restrict__ x,
                      const float* __restrict__ psum, const float* __restrict__ psq,
                      const float* __restrict__ mq, const float* __restrict__ sq,
                      const float* __restrict__ lmda, const int* __restrict__ domain,
                      const int* __restrict__ d1, const int* __restrict__ f1,
                      const int* __restrict__ offsets,
                      float* __restrict__ out) {
    const int blk = blockIdx.x;            // b*LCH + ch
    const int b = blk >> 4, ch = blk & (LCH - 1);
    const int tid = threadIdx.x;
    const int c4 = tid;                    // 0..127 (float4 column index)

    __shared__ int dom_s[BB];
    __shared__ int pos_s[BB];
    __shared__ int src_sh;
    if (tid < BB) dom_s[tid] = domain[tid];
    __syncthreads();
    if (tid < BB) {
        const int d = dom_s[tid];
        int rank = 0;
        for (int j = 0; j < tid; ++j) rank += (dom_s[j] == d) ? 1 : 0;
        pos_s[tid] = (offsets[d] + rank) & (CAP - 1);
    }
    __syncthreads();
    if (tid == 0) {
        const int dd = d1[b], ff = f1[b];
        int s = -1;
        for (int j = 0; j < BB; ++j)
            if (dom_s[j] == dd && pos_s[j] == ff) s = j;
        src_sh = s;
    }
    __syncthreads();

    f32x4 m, g;
    reduce_stats(psum, psq, b, c4, m, g);

    const int s = src_sh;
    f32x4 m1, g1;
    if (s >= 0) {
        reduce_stats(psum, psq, s, c4, m1, g1);
    } else {
        const size_t base = ((size_t)d1[b] * CAP + (size_t)f1[b]) * CC + c4 * 4;
        m1 = *(const f32x4*)(mq + base);
        g1 = *(const f32x4*)(sq + base);
    }

    const float lm = lmda[b];
    const float om = 1.0f - lm;
    f32x4 sc, sh;
#pragma unroll
    for (int j = 0; j < 4; ++j) {
        const float mm = m[j] * lm + m1[j] * om;
        const float gm = g[j] * lm + g1[j] * om;
        sc[j] = gm / g[j];
        sh[j] = mm - m[j] * sc[j];
    }

    // apply to own 64 rows
    const f32x4* xp = (const f32x4*)(x   + ((size_t)b * LL + (size_t)ch * LPC) * CC) + c4;
    f32x4*       op = (f32x4*)(out       + ((size_t)b * LL + (size_t)ch * LPC) * CC) + c4;
#pragma unroll 8
    for (int l = 0; l < LPC; ++l) {
        const f32x4 v = xp[(size_t)l * (CC / 4)];
        f32x4 o;
#pragma unroll
        for (int j = 0; j < 4; ++j) o[j] = fmaf(v[j], sc[j], sh[j]);
        __builtin_nontemporal_store(o, op + (size_t)l * (CC / 4));
    }
}

extern "C" void kernel_launch(void* const* d_in, const int* in_sizes, int n_in,
                              void* d_out, int out_size, void* d_ws, size_t ws_size,
                              hipStream_t stream) {
    const float* x       = (const float*)d_in[0];
    const int*   domain  = (const int*)d_in[1];
    const float* mq      = (const float*)d_in[2];
    const float* sq      = (const float*)d_in[3];
    const float* lmda    = (const float*)d_in[4];
    const int*   d1      = (const int*)d_in[5];
    const int*   f1      = (const int*)d_in[6];
    const int*   offsets = (const int*)d_in[7];
    float* out = (float*)d_out;

    float* ws     = (float*)d_ws;
    float* f_psum = ws;                 // 524288 floats
    float* f_psq  = f_psum + 524288;    // 524288 floats

    hipLaunchKernelGGL(k_partial, dim3(BB * LCH), dim3(128), 0, stream,
                       x, f_psum, f_psq);
    hipLaunchKernelGGL(k_apply, dim3(BB * LCH), dim3(128), 0, stream,
                       x, f_psum, f_psq, mq, sq, lmda, domain, d1, f1, offsets,
                       out);
}